// Round 3
// baseline (465.510 us; speedup 1.0000x reference)
//
#include <hip/hip_runtime.h>

typedef _Float16 f16;
typedef __attribute__((ext_vector_type(4))) _Float16 f16x4;
typedef __attribute__((ext_vector_type(8))) _Float16 f16x8;
typedef __attribute__((ext_vector_type(4))) float f32x4;

#define Tn 4096
#define DHn 64
#define NFn 256
#define BHn 64
#define TCH 64
#define NCHA 8
#define TBLKA (TCH * NCHA)      // 512
#define GRIDXA (Tn / TBLKA)     // 8
#define NCHB 4
#define TBLKB (TCH * NCHB)      // 256
#define GRIDXB (Tn / TBLKB)     // 16
#define KLD 72                  // f16 leading dim for 64-wide tiles
#define CTLD 264                // ctxT leading dim (f16)
#define CTXBYTES (BHn * 65 * NFn * 4)

static constexpr float DS  = 0.35355339059327379f;  // 64^-0.25
static constexpr float DNS = 0.0625f;               // 0.5*DS^2
static constexpr float QSH = 8.0f;                  // q-side exp shift (cancels in ratio)

// ---------- prep: projf16[nf][dh] = (f16)(DS * proj) ----------
__global__ void prep_proj(const float* __restrict__ P, f16* __restrict__ pf) {
    const int idx = (blockIdx.x * 256 + threadIdx.x) * 4;
    const float4 p = *(const float4*)(P + idx);
    f16x4 h;
    h[0] = (f16)(p.x * DS); h[1] = (f16)(p.y * DS);
    h[2] = (f16)(p.z * DS); h[3] = (f16)(p.w * DS);
    *(f16x4*)(pf + idx) = h;
}

// ---------- Kernel A: ctx[bh][dh][nf] (+s row 64) ----------
__global__ __launch_bounds__(256, 2)
void perf_ctx_v3(const float* __restrict__ K, const float* __restrict__ V,
                 const float* __restrict__ P, float* __restrict__ ctxws)
{
    __shared__ __align__(16) f16 kLDS[TCH * KLD];
    __shared__ __align__(16) f16 vT[DHn * KLD];     // [dh][t]
    __shared__ float dn[TCH];
    __shared__ __align__(16) float redmax[TCH][4];

    const int bh = blockIdx.y, tid = threadIdx.x;
    const int lane = tid & 63, wv = tid >> 6, c = lane & 15, g = lane >> 4;
    const int rb = tid >> 4;  // 0..15

    // proj B-frags (x32): nf = 64wv+16nt+c, dh = 32kc+8g+j
    f16x8 pb[4][2];
#pragma unroll
    for (int nt = 0; nt < 4; nt++)
#pragma unroll
        for (int kc = 0; kc < 2; kc++) {
            const float* s = P + (size_t)(64 * wv + 16 * nt + c) * DHn + 32 * kc + 8 * g;
            f16x8 h;
#pragma unroll
            for (int j = 0; j < 8; j++) h[j] = (f16)(s[j] * DS);
            pb[nt][kc] = h;
        }

    f32x4 cacc[4][4];
#pragma unroll
    for (int a = 0; a < 4; a++)
#pragma unroll
        for (int b = 0; b < 4; b++) cacc[a][b] = (f32x4){0.f, 0.f, 0.f, 0.f};
    float sp[4] = {0.f, 0.f, 0.f, 0.f};

    const float* Kb = K + (size_t)bh * Tn * DHn;
    const float* Vb = V + (size_t)bh * Tn * DHn;
    const int tB = blockIdx.x * TBLKA;

    float4 kq[4], vq[4];
#pragma unroll
    for (int i = 0; i < 4; i++) {
        const int t = tB + 16 * i + rb;
        kq[i] = *(const float4*)(Kb + (size_t)t * DHn + 4 * c);
        vq[i] = *(const float4*)(Vb + (size_t)t * DHn + 4 * c);
    }

    for (int ch = 0; ch < NCHA; ch++) {
        // ---- stage chunk ch from regs ----
#pragma unroll
        for (int i = 0; i < 4; i++) {
            const int r = 16 * i + rb;
            f16x4 hk;
            hk[0] = (f16)kq[i].x; hk[1] = (f16)kq[i].y;
            hk[2] = (f16)kq[i].z; hk[3] = (f16)kq[i].w;
            *(f16x4*)&kLDS[r * KLD + 4 * c] = hk;
            float p = kq[i].x * kq[i].x + kq[i].y * kq[i].y +
                      kq[i].z * kq[i].z + kq[i].w * kq[i].w;
            p += __shfl_xor(p, 1); p += __shfl_xor(p, 2);
            p += __shfl_xor(p, 4); p += __shfl_xor(p, 8);
            if (c == 0) dn[r] = p * DNS;
            vT[(4 * c + 0) * KLD + r] = (f16)vq[i].x;
            vT[(4 * c + 1) * KLD + r] = (f16)vq[i].y;
            vT[(4 * c + 2) * KLD + r] = (f16)vq[i].z;
            vT[(4 * c + 3) * KLD + r] = (f16)vq[i].w;
        }
        __syncthreads();  // S1

        // ---- prefetch chunk ch+1 ----
        if (ch + 1 < NCHA) {
            const int t0n = tB + (ch + 1) * TCH;
#pragma unroll
            for (int i = 0; i < 4; i++) {
                const int t = t0n + 16 * i + rb;
                kq[i] = *(const float4*)(Kb + (size_t)t * DHn + 4 * c);
                vq[i] = *(const float4*)(Vb + (size_t)t * DHn + 4 * c);
            }
        }

        // ---- GEMM1: dp[t][nf] ----
        f32x4 dp[4][4];
#pragma unroll
        for (int a = 0; a < 4; a++)
#pragma unroll
            for (int b = 0; b < 4; b++) dp[a][b] = (f32x4){0.f, 0.f, 0.f, 0.f};
#pragma unroll
        for (int mt = 0; mt < 4; mt++) {
            const f16x8 a0 = *(const f16x8*)&kLDS[(16 * mt + c) * KLD + 8 * g];
            const f16x8 a1 = *(const f16x8*)&kLDS[(16 * mt + c) * KLD + 32 + 8 * g];
#pragma unroll
            for (int nt = 0; nt < 4; nt++) {
                dp[mt][nt] = __builtin_amdgcn_mfma_f32_16x16x32_f16(a0, pb[nt][0], dp[mt][nt], 0, 0, 0);
                dp[mt][nt] = __builtin_amdgcn_mfma_f32_16x16x32_f16(a1, pb[nt][1], dp[mt][nt], 0, 0, 0);
            }
        }
        // per-t max over this wave's 64 nf
#pragma unroll
        for (int mt = 0; mt < 4; mt++)
#pragma unroll
            for (int r = 0; r < 4; r++) {
                float m = fmaxf(fmaxf(dp[mt][0][r], dp[mt][1][r]),
                                fmaxf(dp[mt][2][r], dp[mt][3][r]));
                m = fmaxf(m, __shfl_xor(m, 1)); m = fmaxf(m, __shfl_xor(m, 2));
                m = fmaxf(m, __shfl_xor(m, 4)); m = fmaxf(m, __shfl_xor(m, 8));
                if (c == 0) redmax[16 * mt + 4 * g + r][wv] = m;
            }
        __syncthreads();  // S2

        // ---- exp + GEMM2 (w stays in regs: C-layout == x16 A-layout) ----
#pragma unroll
        for (int mt = 0; mt < 4; mt++) {
            float mx[4];
#pragma unroll
            for (int r = 0; r < 4; r++) {
                const int t = 16 * mt + 4 * g + r;
                const f32x4 rm = *(const f32x4*)&redmax[t][0];
                mx[r] = fmaxf(fmaxf(rm[0], rm[1]), fmaxf(rm[2], rm[3])) + dn[t];
            }
            f16x4 hw[4];
#pragma unroll
            for (int nt = 0; nt < 4; nt++)
#pragma unroll
                for (int r = 0; r < 4; r++) {
                    const float w = __expf(dp[mt][nt][r] - mx[r]);
                    sp[nt] += w;
                    hw[nt][r] = (f16)w;
                }
            f16x4 vf[4];
#pragma unroll
            for (int b = 0; b < 4; b++)
                vf[b] = *(const f16x4*)&vT[(16 * b + c) * KLD + 16 * mt + 4 * g];
#pragma unroll
            for (int nt = 0; nt < 4; nt++)
#pragma unroll
                for (int b = 0; b < 4; b++)
                    cacc[nt][b] = __builtin_amdgcn_mfma_f32_16x16x16f16(
                        hw[nt], vf[b], cacc[nt][b], 0, 0, 0);
        }
        __syncthreads();  // Send
    }

    float* cb = ctxws + (size_t)bh * 65 * NFn;
#pragma unroll
    for (int a = 0; a < 4; a++)
#pragma unroll
        for (int b = 0; b < 4; b++)
#pragma unroll
            for (int r = 0; r < 4; r++)
                atomicAdd(&cb[(size_t)(16 * b + c) * NFn + 64 * wv + 16 * a + 4 * g + r],
                          cacc[a][b][r]);
#pragma unroll
    for (int nt = 0; nt < 4; nt++) {
        float sv = sp[nt];
        sv += __shfl_xor(sv, 16); sv += __shfl_xor(sv, 32);
        if (g == 0) atomicAdd(&cb[64 * NFn + 64 * wv + 16 * nt + c], sv);
    }
}

// ---------- Kernel B: out[t][dh] = (exp(qp) . ctx) / (exp(qp) . s), barrier-free K-loop ----------
__global__ __launch_bounds__(256, 2)
void perf_out_v3(const float* __restrict__ Q, const f16* __restrict__ projf16,
                 const float* __restrict__ ctxws, float* __restrict__ Out)
{
    __shared__ __align__(16) f16 ctxT[DHn * CTLD];  // [dh][nf]
    __shared__ float sLDS[NFn];

    const int bh = blockIdx.y, tid = threadIdx.x;
    const int lane = tid & 63, wv = tid >> 6, c = lane & 15, g = lane >> 4;

    // stage ctx^T (f32 -> f16) and s
    const float* cb = ctxws + (size_t)bh * 65 * NFn;
    {
        const int dh = tid >> 2, n0 = (tid & 3) * 64;
#pragma unroll
        for (int u = 0; u < 16; u++) {
            const float4 cv = *(const float4*)&cb[(size_t)dh * NFn + n0 + 4 * u];
            f16x4 h;
            h[0] = (f16)cv.x; h[1] = (f16)cv.y; h[2] = (f16)cv.z; h[3] = (f16)cv.w;
            *(f16x4*)&ctxT[dh * CTLD + n0 + 4 * u] = h;
        }
        sLDS[tid] = cb[64 * NFn + tid];
    }

    // proj A-frags (x32) resident: nf = 16u+c, dh = 32kc+8g+j
    f16x8 pa[16][2];
#pragma unroll
    for (int u = 0; u < 16; u++)
#pragma unroll
        for (int kc = 0; kc < 2; kc++)
            pa[u][kc] = *(const f16x8*)&projf16[(size_t)(16 * u + c) * DHn + 32 * kc + 8 * g];
    __syncthreads();

    const float* Qb = Q + (size_t)bh * Tn * DHn;
    float* Ob = Out + (size_t)bh * Tn * DHn;

    for (int ch = 0; ch < NCHB; ch++) {
        const int tb = blockIdx.x * TBLKB + ch * TCH + 16 * wv;  // wave-owned 16 t
        // q^T B-frags straight from global: t = tb+c, dh = 32kc+8g+j
        f16x8 qf[2];
#pragma unroll
        for (int kc = 0; kc < 2; kc++) {
            const float* qs = Qb + (size_t)(tb + c) * DHn + 32 * kc + 8 * g;
            const float4 q0 = *(const float4*)qs;
            const float4 q1 = *(const float4*)(qs + 4);
            f16x8 h;
            h[0] = (f16)q0.x; h[1] = (f16)q0.y; h[2] = (f16)q0.z; h[3] = (f16)q0.w;
            h[4] = (f16)q1.x; h[5] = (f16)q1.y; h[6] = (f16)q1.z; h[7] = (f16)q1.w;
            qf[kc] = h;
        }

        // GEMM1 (transposed): dp[u] = D[nf 16-tile u][t 16] 
        f32x4 dp[16];
#pragma unroll
        for (int u = 0; u < 16; u++) {
            f32x4 z = (f32x4){0.f, 0.f, 0.f, 0.f};
            z = __builtin_amdgcn_mfma_f32_16x16x32_f16(pa[u][0], qf[0], z, 0, 0, 0);
            z = __builtin_amdgcn_mfma_f32_16x16x32_f16(pa[u][1], qf[1], z, 0, 0, 0);
            dp[u] = z;
        }

        // exp + den + GEMM2 (w regs are x16 A-frags; ctxT frags are B)
        f32x4 oacc[4];
#pragma unroll
        for (int b = 0; b < 4; b++) oacc[b] = (f32x4){0.f, 0.f, 0.f, 0.f};
        float den = 0.f;
#pragma unroll
        for (int u = 0; u < 16; u++) {
            const float4 s4 = *(const float4*)&sLDS[16 * u + 4 * g];
            f16x4 wa;
            {
                const float w0 = __expf(dp[u][0] - QSH);
                const float w1 = __expf(dp[u][1] - QSH);
                const float w2 = __expf(dp[u][2] - QSH);
                const float w3 = __expf(dp[u][3] - QSH);
                den += w0 * s4.x + w1 * s4.y + w2 * s4.z + w3 * s4.w;
                wa[0] = (f16)w0; wa[1] = (f16)w1; wa[2] = (f16)w2; wa[3] = (f16)w3;
            }
#pragma unroll
            for (int b = 0; b < 4; b++) {
                const f16x4 bf = *(const f16x4*)&ctxT[(16 * b + c) * CTLD + 16 * u + 4 * g];
                oacc[b] = __builtin_amdgcn_mfma_f32_16x16x16f16(wa, bf, oacc[b], 0, 0, 0);
            }
        }
        // den currently per (t=tb+c, g-slice) -> reduce over g, then fetch per out-row
        den += __shfl_xor(den, 16);
        den += __shfl_xor(den, 32);
        float dinv[4];
#pragma unroll
        for (int r = 0; r < 4; r++) dinv[r] = 1.0f / __shfl(den, 4 * g + r);
        // store: t = tb+4g+r, dh = 16b+c
#pragma unroll
        for (int r = 0; r < 4; r++) {
            float* orow = Ob + (size_t)(tb + 4 * g + r) * DHn + c;
#pragma unroll
            for (int b = 0; b < 4; b++)
                orow[16 * b] = oacc[b][r] * dinv[r];
        }
    }
}

extern "C" void kernel_launch(void* const* d_in, const int* in_sizes, int n_in,
                              void* d_out, int out_size, void* d_ws, size_t ws_size,
                              hipStream_t stream) {
    const float* q    = (const float*)d_in[0];
    const float* k    = (const float*)d_in[1];
    const float* v    = (const float*)d_in[2];
    const float* proj = (const float*)d_in[3];
    float* out = (float*)d_out;
    float* ctx = (float*)d_ws;
    f16* projf16 = (f16*)((char*)d_ws + CTXBYTES);

    (void)in_sizes; (void)n_in; (void)out_size; (void)ws_size;

    hipMemsetAsync(ctx, 0, CTXBYTES, stream);
    prep_proj<<<16, 256, 0, stream>>>(proj, projf16);
    perf_ctx_v3<<<dim3(GRIDXA, BHn), 256, 0, stream>>>(k, v, proj, ctx);
    perf_out_v3<<<dim3(GRIDXB, BHn), 256, 0, stream>>>(q, projf16, ctx, out);
}